// Round 2
// baseline (2776.745 us; speedup 1.0000x reference)
//
#include <hip/hip_runtime.h>
#include <hip/hip_fp16.h>

// NeRV trilinear splat, v5.
// v4 verdict: occupancy 45->90% bought only 15% (536->455us). LDS fp-atomic pipe
// confirmed as serializer: 393K atomic lane-ops/CU at a flat ~2.5-2.8 cy/lane-op,
// independent of occupancy. Floor with 8 LDS atomics/point is ~450us.
// v5: pipe-split. Phase 1 splats 60% of records + all cell-boundary records into
// the LDS tile (as v4); flush + threadfence; phase 2 splats the remaining 40%
// (interior-only) via unsafeAtomicAdd straight to out — cell working set is 16KB
// -> L2-hot global atomics on an INDEPENDENT pipe, overlapped across the 8
// resident blocks. No precision change (all f32). beta=0.6 hedges a slow L2 pipe.

#define V 256
#define VOLSZ (V * V * V)              // 16,777,216
#define LOG2P 22
#define NPTS (3 << LOG2P)              // 12,582,912
#define NBLK 512                       // blocks for count/scatter
#define PPB (NPTS / NBLK)              // 24,576
#define PITER (PPB / 256)              // 96
#define NBINS 8192                     // 2 groups * 4096 cells (16^3 voxels)
#define NCPG 4096                      // cells per group: 16 x 16 x 16
// tile: (x 17) x (y 17) x (z 17), x fastest
#define TX 17
#define TXY (TX * 17)                  // 289
#define TILE3 (TXY * 17)               // 4913 floats = 19.7 KB
#define TILE3P 4916                    // padded to /4 for float4 zeroing
#define HALO 817                       // 4913 - 16*16*16

// workspace layout (bytes)
#define R_OFF 0ULL
#define R_BYTES (8ULL * NPTS)                       // packed records (100.7 MB)
#define P_OFF (R_OFF + R_BYTES)
#define P_BYTES (4ULL * NBLK * NBINS)               // per-block histograms (16.8 MB)
#define T_OFF (P_OFF + P_BYTES)
#define T_BYTES (4ULL * NBINS)
#define B_OFF (T_OFF + T_BYTES)
#define B_BYTES (4ULL * (NBINS + 1) + 28)
#define H_OFF (B_OFF + B_BYTES)
#define H_BYTES (2ULL * NBINS * HALO)               // f16 halo side buffer (13.4 MB)
#define WS_REQ (H_OFF + H_BYTES)                    // ~131 MB

__device__ __forceinline__ void lds_add(float* p, float v) {
    __hip_atomic_fetch_add(p, v, __ATOMIC_RELAXED, __HIP_MEMORY_SCOPE_WORKGROUP);
}

// fixed-point: voxel coord * 2048 (11-bit fraction), 19 bits total.
// cell: 16-voxel in each dim -> cx = X>>15, cy = Y>>15, cz = Z>>15.
__device__ __forceinline__ void point_to_bin(float x, float y, float z,
                                             unsigned& X, unsigned& Y, unsigned& Z,
                                             int& cell) {
    float xf = (x + 1.f) * 127.5f;   // [0, 255]
    float yf = (y + 1.f) * 127.5f;
    float zf = (z + 1.f) * 127.5f;
    X = (unsigned)(int)(xf * 2048.0f);
    Y = (unsigned)(int)(yf * 2048.0f);
    Z = (unsigned)(int)(zf * 2048.0f);
    int cx = (int)(X >> 15), cy = (int)(Y >> 15), cz = (int)(Z >> 15);
    cell = (cz << 8) | (cy << 4) | cx;            // [0, 4096)
}

// ---------------- pass 1: per-block histogram ----------------
__global__ __launch_bounds__(256)
void count_k(const float* __restrict__ pts, unsigned* __restrict__ partials) {
    __shared__ unsigned hist[NBINS];
    for (int j = threadIdx.x; j < NBINS; j += 256) hist[j] = 0u;
    __syncthreads();
    int b = blockIdx.x;
    long long base = (long long)b * PPB;
#pragma unroll 4
    for (int k = 0; k < PITER; ++k) {
        long long i = base + threadIdx.x + k * 256;
        int view = (int)(i >> LOG2P);
        const float* pp = pts + i * 3;
        unsigned X, Y, Z; int cell;
        point_to_bin(pp[0], pp[1], pp[2], X, Y, Z, cell);
        int bin = ((view < 2) ? 0 : NCPG) + cell;
        atomicAdd(&hist[bin], 1u);
    }
    __syncthreads();
    for (int j = threadIdx.x; j < NBINS; j += 256)
        partials[(size_t)b * NBINS + j] = hist[j];
}

// ---------------- pass 2a: bin totals ----------------
__global__ __launch_bounds__(256)
void totals_k(const unsigned* __restrict__ partials, unsigned* __restrict__ totals) {
    int bin = blockIdx.x * 256 + threadIdx.x;
    unsigned s = 0;
#pragma unroll 8
    for (int k = 0; k < NBLK; ++k) s += partials[(size_t)k * NBINS + bin];
    totals[bin] = s;
}

// ---------------- pass 2b: exclusive scan of totals -> bases[NBINS+1] ----------------
__global__ __launch_bounds__(1024)
void scan_k(const unsigned* __restrict__ totals, unsigned* __restrict__ bases) {
    __shared__ unsigned chunk[1024];
    int t = threadIdx.x;
    unsigned v[NBINS / 1024]; unsigned run = 0;
#pragma unroll
    for (int j = 0; j < NBINS / 1024; ++j) { v[j] = totals[t * (NBINS / 1024) + j]; run += v[j]; }
    chunk[t] = run;
    __syncthreads();
    for (int off = 1; off < 1024; off <<= 1) {
        unsigned add = (t >= off) ? chunk[t - off] : 0u;
        __syncthreads();
        chunk[t] += add;
        __syncthreads();
    }
    unsigned excl = (t == 0) ? 0u : chunk[t - 1];
    unsigned r = excl;
    if (t == 0) bases[0] = 0u;
#pragma unroll
    for (int j = 0; j < NBINS / 1024; ++j) { r += v[j]; bases[t * (NBINS / 1024) + 1 + j] = r; }
}

// ---------------- pass 2c: per-(block,bin) start offsets, in place ----------------
__global__ __launch_bounds__(256)
void offsets_k(unsigned* __restrict__ partials, const unsigned* __restrict__ bases) {
    int bin = blockIdx.x * 256 + threadIdx.x;
    unsigned run = bases[bin];
#pragma unroll 8
    for (int k = 0; k < NBLK; ++k) {
        unsigned c = partials[(size_t)k * NBINS + bin];
        partials[(size_t)k * NBINS + bin] = run;
        run += c;
    }
}

// ---------------- pass 3: scatter points into bin-sorted 8B records ----------------
// record: lo = lx15 | ly15<<15 | (Z&3)<<30 ; hi = (Z>>2)&0x1FFF | f16<<16
__global__ __launch_bounds__(256)
void scatter_k(const float* __restrict__ pts, const float* __restrict__ feat,
               const unsigned* __restrict__ offsets,
               unsigned long long* __restrict__ recs) {
    __shared__ unsigned cur[NBINS];
    int b = blockIdx.x;
    for (int j = threadIdx.x; j < NBINS; j += 256)
        cur[j] = offsets[(size_t)b * NBINS + j];
    __syncthreads();
    long long base = (long long)b * PPB;
#pragma unroll 2
    for (int k = 0; k < PITER; ++k) {
        long long i = base + threadIdx.x + k * 256;
        int view = (int)(i >> LOG2P);
        const float* pp = pts + i * 3;
        unsigned X, Y, Z; int cell;
        point_to_bin(pp[0], pp[1], pp[2], X, Y, Z, cell);
        int bin = ((view < 2) ? 0 : NCPG) + cell;
        float wv = feat[i] * ((view < 2) ? 0.5f : 1.0f);
        unsigned hw = __half_as_ushort(__float2half(wv));
        unsigned lo = (X & 0x7FFFu) | ((Y & 0x7FFFu) << 15) | ((Z & 3u) << 30);
        unsigned hi = ((Z >> 2) & 0x1FFFu) | (hw << 16);
        unsigned slot = atomicAdd(&cur[bin], 1u);
        recs[slot] = (unsigned long long)lo | ((unsigned long long)hi << 32);
    }
}

// ---------------- pass 4: per-cell splat (LDS pipe + L2 global-atomic pipe) ----------------
__device__ __forceinline__ bool rec_boundary(unsigned long long a) {
    unsigned lo = (unsigned)a, hi = (unsigned)(a >> 32);
    unsigned lx = (lo & 0x7FFFu) >> 11;
    unsigned ly = ((lo >> 15) & 0x7FFFu) >> 11;
    unsigned lz = (((hi & 0x1FFFu) << 2) | (lo >> 30)) >> 11;
    return (lx == 15u) | (ly == 15u) | (lz == 15u);
}

__device__ __forceinline__ void splat_rec(unsigned long long a, float* tile) {
    unsigned lo = (unsigned)a, hi = (unsigned)(a >> 32);
    unsigned lxf = lo & 0x7FFFu;                       // 4.11
    unsigned lyf = (lo >> 15) & 0x7FFFu;               // 4.11
    unsigned lzf = ((hi & 0x1FFFu) << 2) | (lo >> 30); // 4.11
    float w = __half2float(__ushort_as_half((unsigned short)(hi >> 16)));
    int lx = lxf >> 11, ly = lyf >> 11, lz = lzf >> 11;
    float fx = (lxf & 2047u) * (1.f / 2048.f);
    float fy = (lyf & 2047u) * (1.f / 2048.f);
    float fz = (lzf & 2047u) * (1.f / 2048.f);
    float wx0 = 1.f - fx, wy0 = 1.f - fy, wz0 = 1.f - fz;
    int t0 = (lz * 17 + ly) * TX + lx;
    float w00 = w * wz0 * wy0, w01 = w * wz0 * fy;
    float w10 = w * fz * wy0,  w11 = w * fz * fy;
    lds_add(&tile[t0],                w00 * wx0);
    lds_add(&tile[t0 + 1],            w00 * fx);
    lds_add(&tile[t0 + TX],           w01 * wx0);
    lds_add(&tile[t0 + TX + 1],       w01 * fx);
    lds_add(&tile[t0 + TXY],          w10 * wx0);
    lds_add(&tile[t0 + TXY + 1],      w10 * fx);
    lds_add(&tile[t0 + TXY + TX],     w11 * wx0);
    lds_add(&tile[t0 + TXY + TX + 1], w11 * fx);
}

__device__ __forceinline__ void splat_global(unsigned long long a, float* __restrict__ outc) {
    // outc = &out[cell origin]; record is interior (lx,ly,lz <= 14) so all 8
    // targets stay inside this cell -> no cross-block hazard.
    unsigned lo = (unsigned)a, hi = (unsigned)(a >> 32);
    unsigned lxf = lo & 0x7FFFu;
    unsigned lyf = (lo >> 15) & 0x7FFFu;
    unsigned lzf = ((hi & 0x1FFFu) << 2) | (lo >> 30);
    float w = __half2float(__ushort_as_half((unsigned short)(hi >> 16)));
    int lx = lxf >> 11, ly = lyf >> 11, lz = lzf >> 11;
    float fx = (lxf & 2047u) * (1.f / 2048.f);
    float fy = (lyf & 2047u) * (1.f / 2048.f);
    float fz = (lzf & 2047u) * (1.f / 2048.f);
    float wx0 = 1.f - fx, wy0 = 1.f - fy, wz0 = 1.f - fz;
    float* p = outc + ((lz * V + ly) * V + lx);
    float w00 = w * wz0 * wy0, w01 = w * wz0 * fy;
    float w10 = w * fz * wy0,  w11 = w * fz * fy;
    unsafeAtomicAdd(p,                 w00 * wx0);
    unsafeAtomicAdd(p + 1,             w00 * fx);
    unsafeAtomicAdd(p + V,             w01 * wx0);
    unsafeAtomicAdd(p + V + 1,         w01 * fx);
    unsafeAtomicAdd(p + V * V,         w10 * wx0);
    unsafeAtomicAdd(p + V * V + 1,     w10 * fx);
    unsafeAtomicAdd(p + V * V + V,     w11 * wx0);
    unsafeAtomicAdd(p + V * V + V + 1, w11 * fx);
}

__global__ __launch_bounds__(256)
void splat_cells_k(const unsigned long long* __restrict__ recs,
                   const unsigned* __restrict__ bases,
                   float* __restrict__ out, __half* __restrict__ halo) {
    __shared__ __align__(16) float tile[TILE3P];
    int bid = blockIdx.x;
    unsigned s = bases[bid], e = bases[bid + 1];
    unsigned n = e - s;
    unsigned m = s + (n * 3u) / 5u;     // beta_pos = 0.6: 60% head -> LDS pipe

    float4* t4 = (float4*)tile;
    float4 z4 = make_float4(0.f, 0.f, 0.f, 0.f);
    for (int j = threadIdx.x; j < TILE3P / 4; j += 256) t4[j] = z4;
    __syncthreads();

    // phase 1a: head records, all 8 corners into LDS tile
    for (unsigned i = s + threadIdx.x; i < m; i += 256)
        splat_rec(recs[i], tile);
    // phase 1b: tail records that touch a cell boundary must use the tile
    // (their halo-plane contributions flow through the halo export)
    for (unsigned i = m + threadIdx.x; i < e; i += 256) {
        unsigned long long a = recs[i];
        if (rec_boundary(a)) splat_rec(a, tile);
    }
    __syncthreads();

    // flush tile -> out interior (plain store) + halo (f16)
    int g = bid >> 12, cc = bid & (NCPG - 1);
    int cx = cc & 15, cy = (cc >> 4) & 15, cz = cc >> 8;
    int ox = cx * 16, oy = cy * 16, oz = cz * 16;
    size_t obase = (size_t)g * VOLSZ;
    for (int idx = threadIdx.x; idx < TILE3; idx += 256) {
        int lz = idx / TXY;
        int r = idx - lz * TXY;
        int ly = r / TX;
        int lx = r - ly * TX;
        float val = tile[idx];
        if (lx < 16 && ly < 16 && lz < 16) {
            out[obase + ((size_t)(oz + lz) * V + (oy + ly)) * V + (ox + lx)] = val;
        } else {
            int h;
            if (lx == 16)      h = ly * 17 + lz;              // 17*17 = 289
            else if (ly == 16) h = 289 + lx * 17 + lz;        // 16*17 = 272
            else               h = 561 + lx * 16 + ly;        // 16*16 = 256
            halo[(size_t)bid * HALO + h] = __float2half(val);
        }
    }

    // all flush stores must reach L2 before any phase-2 atomic to the same cell
    __threadfence();
    __syncthreads();

    // phase 2: interior tail records via L2-hot global atomics (independent pipe)
    float* outc = out + obase + ((size_t)oz * V + oy) * V + ox;
    for (unsigned i = m + threadIdx.x; i < e; i += 256) {
        unsigned long long a = recs[i];
        if (!rec_boundary(a)) splat_global(a, outc);
    }
}

// ---------------- pass 5: add halo contributions on cell-boundary planes ----------------
__device__ __forceinline__ int hidx(int px, int py, int pz) {
    if (px == 16) return py * 17 + pz;
    if (py == 16) return 289 + px * 17 + pz;
    return 561 + px * 16 + py;
}

__global__ __launch_bounds__(256)
void halo_k(const __half* __restrict__ halo, float* __restrict__ out) {
    unsigned tid = blockIdx.x * 256 + threadIdx.x;   // 2^25 threads
    unsigned g = tid >> 24;
    unsigned v = tid & 0xFFFFFFu;
    int vx = v & 255, vy = (v >> 8) & 255, vz = v >> 16;
    int lx = vx & 15, ly = vy & 15, lz = vz & 15;
    int cx = vx >> 4, cy = vy >> 4, cz = vz >> 4;
    bool ax = (lx == 0) && (cx > 0);
    bool ay = (ly == 0) && (cy > 0);
    bool az = (lz == 0) && (cz > 0);
    if (!(ax || ay || az)) return;
    auto cellBase = [&](int ccx, int ccy, int ccz) {
        return (size_t)((g << 12) | (ccz << 8) | (ccy << 4) | ccx) * HALO;
    };
    float acc = 0.f;
    if (ax)             acc += __half2float(halo[cellBase(cx - 1, cy, cz) + hidx(16, ly, lz)]);
    if (ay)             acc += __half2float(halo[cellBase(cx, cy - 1, cz) + hidx(lx, 16, lz)]);
    if (az)             acc += __half2float(halo[cellBase(cx, cy, cz - 1) + hidx(lx, ly, 16)]);
    if (ax && ay)       acc += __half2float(halo[cellBase(cx - 1, cy - 1, cz) + hidx(16, 16, lz)]);
    if (ax && az)       acc += __half2float(halo[cellBase(cx - 1, cy, cz - 1) + hidx(16, ly, 16)]);
    if (ay && az)       acc += __half2float(halo[cellBase(cx, cy - 1, cz - 1) + hidx(lx, 16, 16)]);
    if (ax && ay && az) acc += __half2float(halo[cellBase(cx - 1, cy - 1, cz - 1) + hidx(16, 16, 16)]);
    out[(size_t)g * VOLSZ + v] += acc;
}

// ---------------- fallback (ws too small): direct atomic path ----------------
__global__ __launch_bounds__(256)
void zero_f4(float4* __restrict__ p, int n4) {
    int i = blockIdx.x * blockDim.x + threadIdx.x;
    if (i < n4) p[i] = make_float4(0.f, 0.f, 0.f, 0.f);
}

__global__ __launch_bounds__(256)
void splat_direct(const float* __restrict__ pts, const float* __restrict__ feat,
                  float* __restrict__ out) {
    int i = blockIdx.x * blockDim.x + threadIdx.x;
    if (i >= NPTS) return;
    int b = i >> LOG2P;
    const float* pp = pts + (long long)i * 3;
    float scale = (b < 2) ? 0.5f : 1.0f;
    float* dst = out + ((b < 2) ? 0 : VOLSZ);
    float xf = (pp[0] + 1.f) * 127.5f, yf = (pp[1] + 1.f) * 127.5f, zf = (pp[2] + 1.f) * 127.5f;
    float lxf = floorf(xf), lyf = floorf(yf), lzf = floorf(zf);
    float fx = xf - lxf, fy = yf - lyf, fz = zf - lzf;
    int ix = (int)lxf, iy = (int)lyf, iz = (int)lzf;
    float wv = feat[i] * scale;
    float wx[2] = {1.f - fx, fx}, wy[2] = {1.f - fy, fy}, wz[2] = {1.f - fz, fz};
#pragma unroll
    for (int dz = 0; dz < 2; ++dz) {
        int z2 = iz + dz; if ((unsigned)z2 >= (unsigned)V) continue;
#pragma unroll
        for (int dy = 0; dy < 2; ++dy) {
            int y2 = iy + dy; if ((unsigned)y2 >= (unsigned)V) continue;
            float wzy = wz[dz] * wy[dy] * wv;
            int base = (z2 * V + y2) * V;
#pragma unroll
            for (int dx = 0; dx < 2; ++dx) {
                int x2 = ix + dx; if ((unsigned)x2 >= (unsigned)V) continue;
                unsafeAtomicAdd(dst + base + x2, wzy * wx[dx]);
            }
        }
    }
}

extern "C" void kernel_launch(void* const* d_in, const int* in_sizes, int n_in,
                              void* d_out, int out_size, void* d_ws, size_t ws_size,
                              hipStream_t stream) {
    const float* pts  = (const float*)d_in[0];
    const float* feat = (const float*)d_in[1];
    float* out = (float*)d_out;

    if (ws_size < WS_REQ) {
        int n4 = out_size / 4;
        zero_f4<<<(n4 + 255) / 256, 256, 0, stream>>>((float4*)out, n4);
        splat_direct<<<(NPTS + 255) / 256, 256, 0, stream>>>(pts, feat, out);
        return;
    }

    char* ws = (char*)d_ws;
    unsigned long long* recs = (unsigned long long*)(ws + R_OFF);
    unsigned* partials       = (unsigned*)(ws + P_OFF);
    unsigned* totals         = (unsigned*)(ws + T_OFF);
    unsigned* bases          = (unsigned*)(ws + B_OFF);
    __half* halo             = (__half*)(ws + H_OFF);

    count_k  <<<NBLK, 256, 0, stream>>>(pts, partials);
    totals_k <<<NBINS / 256, 256, 0, stream>>>(partials, totals);
    scan_k   <<<1, 1024, 0, stream>>>(totals, bases);
    offsets_k<<<NBINS / 256, 256, 0, stream>>>(partials, bases);
    scatter_k<<<NBLK, 256, 0, stream>>>(pts, feat, partials, recs);
    splat_cells_k<<<NBINS, 256, 0, stream>>>(recs, bases, out, halo);
    halo_k   <<<(1u << 25) / 256, 256, 0, stream>>>(halo, out);
}

// Round 3
// 858.493 us; speedup vs baseline: 3.2344x; 3.2344x over previous
//
#include <hip/hip_runtime.h>
#include <hip/hip_fp16.h>

// NeRV trilinear splat, v6.
// v5 post-mortem: global-atomic pipe-split FAILED — WRITE_SIZE 146MB -> 1.26GB,
// splat 455 -> 2030us. Per-block __threadfence (L2 writeback on gfx9xx) + atomic
// dirty-line thrash made every add an HBM round-trip. Global atomics ruled out.
// v4 baseline restored (scattered LDS f32 atomics: ~2.5-2.8 cy/lane-op, 8/point).
// v6: halve atomic lane-ops with NO precision risk. The x-pair (lx,lx+1) of each
// of the 4 (y,z) corners becomes ONE ds_add_u64 into a packed fixed-point word:
//   [hi_sum:27][lo_sum:27][count:10]
// addends biased non-negative (enc = rn(v*2^13) + 2^17) so fields are monotone and
// never carry across boundaries (<=762 adds before overflow; observed max ~15).
// Odd/even lx alignment solved with two pair-tables (A: even-base, B: odd-base),
// 16 words/row -> 37KB LDS (4 blocks/CU; pipe is rate-bound, occupancy cheap).
// Quantization 1.2e-4/addend, exact integer accumulation -> absmax unchanged.

#define V 256
#define VOLSZ (V * V * V)              // 16,777,216
#define LOG2P 22
#define NPTS (3 << LOG2P)              // 12,582,912
#define NBLK 512                       // blocks for count/scatter
#define PPB (NPTS / NBLK)              // 24,576
#define PITER (PPB / 256)              // 96
#define NBINS 8192                     // 2 groups * 4096 cells (16^3 voxels)
#define NCPG 4096                      // cells per group: 16 x 16 x 16
// value tile logical shape: (x 17) x (y 17) x (z 17), x fastest
#define TX 17
#define TXY (TX * 17)                  // 289
#define TILE3 (TXY * 17)               // 4913 voxel values
#define HALO 817                       // 4913 - 16*16*16
// packed u64 tile: per (z,y) row 16 words = 8 A-pairs (base even) + 8 B-pairs (base odd)
#define TROW 16
#define TWORDS (289 * TROW)            // 4624 u64 = 36,992 B
#define FSCALE 8192.0f                 // 2^13 fixed-point scale
#define FBIAS 131072                   // 2^17 per-addend bias
#define FINV (1.0f / 8192.0f)

// workspace layout (bytes)
#define R_OFF 0ULL
#define R_BYTES (8ULL * NPTS)                       // packed records (100.7 MB)
#define P_OFF (R_OFF + R_BYTES)
#define P_BYTES (4ULL * NBLK * NBINS)               // per-block histograms (16.8 MB)
#define T_OFF (P_OFF + P_BYTES)
#define T_BYTES (4ULL * NBINS)
#define B_OFF (T_OFF + T_BYTES)
#define B_BYTES (4ULL * (NBINS + 1) + 28)
#define H_OFF (B_OFF + B_BYTES)
#define H_BYTES (2ULL * NBINS * HALO)               // f16 halo side buffer (13.4 MB)
#define WS_REQ (H_OFF + H_BYTES)                    // ~131 MB

// fixed-point: voxel coord * 2048 (11-bit fraction), 19 bits total.
// cell: 16-voxel in each dim -> cx = X>>15, cy = Y>>15, cz = Z>>15.
__device__ __forceinline__ void point_to_bin(float x, float y, float z,
                                             unsigned& X, unsigned& Y, unsigned& Z,
                                             int& cell) {
    float xf = (x + 1.f) * 127.5f;   // [0, 255]
    float yf = (y + 1.f) * 127.5f;
    float zf = (z + 1.f) * 127.5f;
    X = (unsigned)(int)(xf * 2048.0f);
    Y = (unsigned)(int)(yf * 2048.0f);
    Z = (unsigned)(int)(zf * 2048.0f);
    int cx = (int)(X >> 15), cy = (int)(Y >> 15), cz = (int)(Z >> 15);
    cell = (cz << 8) | (cy << 4) | cx;            // [0, 4096)
}

// ---------------- pass 1: per-block histogram ----------------
__global__ __launch_bounds__(256)
void count_k(const float* __restrict__ pts, unsigned* __restrict__ partials) {
    __shared__ unsigned hist[NBINS];
    for (int j = threadIdx.x; j < NBINS; j += 256) hist[j] = 0u;
    __syncthreads();
    int b = blockIdx.x;
    long long base = (long long)b * PPB;
#pragma unroll 4
    for (int k = 0; k < PITER; ++k) {
        long long i = base + threadIdx.x + k * 256;
        int view = (int)(i >> LOG2P);
        const float* pp = pts + i * 3;
        unsigned X, Y, Z; int cell;
        point_to_bin(pp[0], pp[1], pp[2], X, Y, Z, cell);
        int bin = ((view < 2) ? 0 : NCPG) + cell;
        atomicAdd(&hist[bin], 1u);
    }
    __syncthreads();
    for (int j = threadIdx.x; j < NBINS; j += 256)
        partials[(size_t)b * NBINS + j] = hist[j];
}

// ---------------- pass 2a: bin totals ----------------
__global__ __launch_bounds__(256)
void totals_k(const unsigned* __restrict__ partials, unsigned* __restrict__ totals) {
    int bin = blockIdx.x * 256 + threadIdx.x;
    unsigned s = 0;
#pragma unroll 8
    for (int k = 0; k < NBLK; ++k) s += partials[(size_t)k * NBINS + bin];
    totals[bin] = s;
}

// ---------------- pass 2b: exclusive scan of totals -> bases[NBINS+1] ----------------
__global__ __launch_bounds__(1024)
void scan_k(const unsigned* __restrict__ totals, unsigned* __restrict__ bases) {
    __shared__ unsigned chunk[1024];
    int t = threadIdx.x;
    unsigned v[NBINS / 1024]; unsigned run = 0;
#pragma unroll
    for (int j = 0; j < NBINS / 1024; ++j) { v[j] = totals[t * (NBINS / 1024) + j]; run += v[j]; }
    chunk[t] = run;
    __syncthreads();
    for (int off = 1; off < 1024; off <<= 1) {
        unsigned add = (t >= off) ? chunk[t - off] : 0u;
        __syncthreads();
        chunk[t] += add;
        __syncthreads();
    }
    unsigned excl = (t == 0) ? 0u : chunk[t - 1];
    unsigned r = excl;
    if (t == 0) bases[0] = 0u;
#pragma unroll
    for (int j = 0; j < NBINS / 1024; ++j) { r += v[j]; bases[t * (NBINS / 1024) + 1 + j] = r; }
}

// ---------------- pass 2c: per-(block,bin) start offsets, in place ----------------
__global__ __launch_bounds__(256)
void offsets_k(unsigned* __restrict__ partials, const unsigned* __restrict__ bases) {
    int bin = blockIdx.x * 256 + threadIdx.x;
    unsigned run = bases[bin];
#pragma unroll 8
    for (int k = 0; k < NBLK; ++k) {
        unsigned c = partials[(size_t)k * NBINS + bin];
        partials[(size_t)k * NBINS + bin] = run;
        run += c;
    }
}

// ---------------- pass 3: scatter points into bin-sorted 8B records ----------------
// record: lo = lx15 | ly15<<15 | (Z&3)<<30 ; hi = (Z>>2)&0x1FFF | f16<<16
__global__ __launch_bounds__(256)
void scatter_k(const float* __restrict__ pts, const float* __restrict__ feat,
               const unsigned* __restrict__ offsets,
               unsigned long long* __restrict__ recs) {
    __shared__ unsigned cur[NBINS];
    int b = blockIdx.x;
    for (int j = threadIdx.x; j < NBINS; j += 256)
        cur[j] = offsets[(size_t)b * NBINS + j];
    __syncthreads();
    long long base = (long long)b * PPB;
#pragma unroll 2
    for (int k = 0; k < PITER; ++k) {
        long long i = base + threadIdx.x + k * 256;
        int view = (int)(i >> LOG2P);
        const float* pp = pts + i * 3;
        unsigned X, Y, Z; int cell;
        point_to_bin(pp[0], pp[1], pp[2], X, Y, Z, cell);
        int bin = ((view < 2) ? 0 : NCPG) + cell;
        float wv = feat[i] * ((view < 2) ? 0.5f : 1.0f);
        unsigned hw = __half_as_ushort(__float2half(wv));
        unsigned lo = (X & 0x7FFFu) | ((Y & 0x7FFFu) << 15) | ((Z & 3u) << 30);
        unsigned hi = ((Z >> 2) & 0x1FFFu) | (hw << 16);
        unsigned slot = atomicAdd(&cur[bin], 1u);
        recs[slot] = (unsigned long long)lo | ((unsigned long long)hi << 32);
    }
}

// ---------------- pass 4: per-cell splat via packed u64 fixed-point atomics ----------------
__device__ __forceinline__ void packadd(unsigned long long* p, float vlo, float vhi) {
    int elo = __float2int_rn(vlo * FSCALE) + FBIAS;
    int ehi = __float2int_rn(vhi * FSCALE) + FBIAS;
    unsigned long long add = ((unsigned long long)(unsigned)ehi << 37)
                           | ((unsigned long long)(unsigned)elo << 10) | 1ull;
    __hip_atomic_fetch_add(p, add, __ATOMIC_RELAXED, __HIP_MEMORY_SCOPE_WORKGROUP);
}

__device__ __forceinline__ void splat_rec(unsigned long long a, unsigned long long* t) {
    unsigned lo = (unsigned)a, hi = (unsigned)(a >> 32);
    unsigned lxf = lo & 0x7FFFu;                       // 4.11
    unsigned lyf = (lo >> 15) & 0x7FFFu;               // 4.11
    unsigned lzf = ((hi & 0x1FFFu) << 2) | (lo >> 30); // 4.11
    float w = __half2float(__ushort_as_half((unsigned short)(hi >> 16)));
    int lx = lxf >> 11, ly = lyf >> 11, lz = lzf >> 11;
    float fx = (lxf & 2047u) * (1.f / 2048.f);
    float fy = (lyf & 2047u) * (1.f / 2048.f);
    float fz = (lzf & 2047u) * (1.f / 2048.f);
    float wx0 = 1.f - fx, wy0 = 1.f - fy, wz0 = 1.f - fz;
    // word select: even lx -> A-word lx/2 (offset 0..7); odd lx -> B-word (lx-1)/2 (offset 8..15)
    int wsel = (lx >> 1) + ((lx & 1) << 3);
    int r00 = (lz * 17 + ly) * TROW + wsel;
    float w00 = w * wz0 * wy0, w01 = w * wz0 * fy;
    float w10 = w * fz * wy0,  w11 = w * fz * fy;
    packadd(&t[r00],                   w00 * wx0, w00 * fx);
    packadd(&t[r00 + TROW],            w01 * wx0, w01 * fx);
    packadd(&t[r00 + 17 * TROW],        w10 * wx0, w10 * fx);
    packadd(&t[r00 + 17 * TROW + TROW], w11 * wx0, w11 * fx);
}

__device__ __forceinline__ float decode_slot(unsigned long long w, bool hi_slot) {
    unsigned k = (unsigned)w & 1023u;
    unsigned f = hi_slot ? (unsigned)(w >> 37) : (unsigned)((w >> 10) & 0x07FFFFFFu);
    return ((int)f - (int)(k * (unsigned)FBIAS)) * FINV;
}

__global__ __launch_bounds__(256)
void splat_cells_k(const unsigned long long* __restrict__ recs,
                   const unsigned* __restrict__ bases,
                   float* __restrict__ out, __half* __restrict__ halo) {
    __shared__ unsigned long long tile[TWORDS];       // 36,992 B
    int bid = blockIdx.x;
    unsigned s = bases[bid], e = bases[bid + 1];
    // hoist first record load above the tile-zero phase (latency hides under it)
    unsigned i0 = s + threadIdx.x;
    unsigned long long pre = (i0 < e) ? recs[i0] : 0ull;

    for (int j = threadIdx.x; j < TWORDS; j += 256) tile[j] = 0ull;
    __syncthreads();

    if (i0 < e) {
        unsigned long long a = pre;
        for (unsigned i = i0 + 256; i < e; i += 256) {
            unsigned long long nxt = recs[i];   // next load in flight during splat
            splat_rec(a, tile);
            a = nxt;
        }
        splat_rec(a, tile);
    }
    __syncthreads();

    int g = bid >> 12, cc = bid & (NCPG - 1);
    int cx = cc & 15, cy = (cc >> 4) & 15, cz = cc >> 8;
    int ox = cx * 16, oy = cy * 16, oz = cz * 16;
    size_t obase = (size_t)g * VOLSZ;
    for (int idx = threadIdx.x; idx < TILE3; idx += 256) {
        int lz = idx / TXY;
        int r = idx - lz * TXY;
        int ly = r / TX;
        int lx = r - ly * TX;
        int rowb = (lz * 17 + ly) * TROW;
        float val = 0.f;
        if (lx < 16)   // A covers x 0..15: word x/2, slot = parity
            val += decode_slot(tile[rowb + (lx >> 1)], (lx & 1) != 0);
        if (lx >= 1)   // B covers x 1..16: word (x-1)/2, slot = !parity
            val += decode_slot(tile[rowb + 8 + ((lx - 1) >> 1)], (lx & 1) == 0);
        if (lx < 16 && ly < 16 && lz < 16) {
            out[obase + ((size_t)(oz + lz) * V + (oy + ly)) * V + (ox + lx)] = val;
        } else {
            int h;
            if (lx == 16)      h = ly * 17 + lz;              // 17*17 = 289
            else if (ly == 16) h = 289 + lx * 17 + lz;        // 16*17 = 272
            else               h = 561 + lx * 16 + ly;        // 16*16 = 256
            halo[(size_t)bid * HALO + h] = __float2half(val);
        }
    }
}

// ---------------- pass 5: add halo contributions on cell-boundary planes ----------------
__device__ __forceinline__ int hidx(int px, int py, int pz) {
    if (px == 16) return py * 17 + pz;
    if (py == 16) return 289 + px * 17 + pz;
    return 561 + px * 16 + py;
}

__global__ __launch_bounds__(256)
void halo_k(const __half* __restrict__ halo, float* __restrict__ out) {
    unsigned tid = blockIdx.x * 256 + threadIdx.x;   // 2^25 threads
    unsigned g = tid >> 24;
    unsigned v = tid & 0xFFFFFFu;
    int vx = v & 255, vy = (v >> 8) & 255, vz = v >> 16;
    int lx = vx & 15, ly = vy & 15, lz = vz & 15;
    int cx = vx >> 4, cy = vy >> 4, cz = vz >> 4;
    bool ax = (lx == 0) && (cx > 0);
    bool ay = (ly == 0) && (cy > 0);
    bool az = (lz == 0) && (cz > 0);
    if (!(ax || ay || az)) return;
    auto cellBase = [&](int ccx, int ccy, int ccz) {
        return (size_t)((g << 12) | (ccz << 8) | (ccy << 4) | ccx) * HALO;
    };
    float acc = 0.f;
    if (ax)             acc += __half2float(halo[cellBase(cx - 1, cy, cz) + hidx(16, ly, lz)]);
    if (ay)             acc += __half2float(halo[cellBase(cx, cy - 1, cz) + hidx(lx, 16, lz)]);
    if (az)             acc += __half2float(halo[cellBase(cx, cy, cz - 1) + hidx(lx, ly, 16)]);
    if (ax && ay)       acc += __half2float(halo[cellBase(cx - 1, cy - 1, cz) + hidx(16, 16, lz)]);
    if (ax && az)       acc += __half2float(halo[cellBase(cx - 1, cy, cz - 1) + hidx(16, ly, 16)]);
    if (ay && az)       acc += __half2float(halo[cellBase(cx, cy - 1, cz - 1) + hidx(lx, 16, 16)]);
    if (ax && ay && az) acc += __half2float(halo[cellBase(cx - 1, cy - 1, cz - 1) + hidx(16, 16, 16)]);
    out[(size_t)g * VOLSZ + v] += acc;
}

// ---------------- fallback (ws too small): direct atomic path ----------------
__global__ __launch_bounds__(256)
void zero_f4(float4* __restrict__ p, int n4) {
    int i = blockIdx.x * blockDim.x + threadIdx.x;
    if (i < n4) p[i] = make_float4(0.f, 0.f, 0.f, 0.f);
}

__global__ __launch_bounds__(256)
void splat_direct(const float* __restrict__ pts, const float* __restrict__ feat,
                  float* __restrict__ out) {
    int i = blockIdx.x * blockDim.x + threadIdx.x;
    if (i >= NPTS) return;
    int b = i >> LOG2P;
    const float* pp = pts + (long long)i * 3;
    float scale = (b < 2) ? 0.5f : 1.0f;
    float* dst = out + ((b < 2) ? 0 : VOLSZ);
    float xf = (pp[0] + 1.f) * 127.5f, yf = (pp[1] + 1.f) * 127.5f, zf = (pp[2] + 1.f) * 127.5f;
    float lxf = floorf(xf), lyf = floorf(yf), lzf = floorf(zf);
    float fx = xf - lxf, fy = yf - lyf, fz = zf - lzf;
    int ix = (int)lxf, iy = (int)lyf, iz = (int)lzf;
    float wv = feat[i] * scale;
    float wx[2] = {1.f - fx, fx}, wy[2] = {1.f - fy, fy}, wz[2] = {1.f - fz, fz};
#pragma unroll
    for (int dz = 0; dz < 2; ++dz) {
        int z2 = iz + dz; if ((unsigned)z2 >= (unsigned)V) continue;
#pragma unroll
        for (int dy = 0; dy < 2; ++dy) {
            int y2 = iy + dy; if ((unsigned)y2 >= (unsigned)V) continue;
            float wzy = wz[dz] * wy[dy] * wv;
            int base = (z2 * V + y2) * V;
#pragma unroll
            for (int dx = 0; dx < 2; ++dx) {
                int x2 = ix + dx; if ((unsigned)x2 >= (unsigned)V) continue;
                unsafeAtomicAdd(dst + base + x2, wzy * wx[dx]);
            }
        }
    }
}

extern "C" void kernel_launch(void* const* d_in, const int* in_sizes, int n_in,
                              void* d_out, int out_size, void* d_ws, size_t ws_size,
                              hipStream_t stream) {
    const float* pts  = (const float*)d_in[0];
    const float* feat = (const float*)d_in[1];
    float* out = (float*)d_out;

    if (ws_size < WS_REQ) {
        int n4 = out_size / 4;
        zero_f4<<<(n4 + 255) / 256, 256, 0, stream>>>((float4*)out, n4);
        splat_direct<<<(NPTS + 255) / 256, 256, 0, stream>>>(pts, feat, out);
        return;
    }

    char* ws = (char*)d_ws;
    unsigned long long* recs = (unsigned long long*)(ws + R_OFF);
    unsigned* partials       = (unsigned*)(ws + P_OFF);
    unsigned* totals         = (unsigned*)(ws + T_OFF);
    unsigned* bases          = (unsigned*)(ws + B_OFF);
    __half* halo             = (__half*)(ws + H_OFF);

    count_k  <<<NBLK, 256, 0, stream>>>(pts, partials);
    totals_k <<<NBINS / 256, 256, 0, stream>>>(partials, totals);
    scan_k   <<<1, 1024, 0, stream>>>(totals, bases);
    offsets_k<<<NBINS / 256, 256, 0, stream>>>(partials, bases);
    scatter_k<<<NBLK, 256, 0, stream>>>(pts, feat, partials, recs);
    splat_cells_k<<<NBINS, 256, 0, stream>>>(recs, bases, out, halo);
    halo_k   <<<(1u << 25) / 256, 256, 0, stream>>>(halo, out);
}

// Round 4
// 781.551 us; speedup vs baseline: 3.5529x; 1.0984x over previous
//
#include <hip/hip_runtime.h>
#include <hip/hip_fp16.h>

// NeRV trilinear splat, v7.
// v6 verdict: packed u64 fixed-point LDS atomics halved the splat as predicted
// (total 1226 -> 858us, absmax unchanged). New #1: scatter_k 348us, VALUBusy 3%,
// occ 22.5%, HBM 18% -> latency-bound on the RETURNING cursor atomic
// (ds_add_rtn_u32 ~200cy, 1 in flight per wave). WRITE_SIZE 381MB (3.8x records)
// is partial-sector RMW but traffic is NOT the limit (499MB ~= 80us at BW).
// v7: break the cursor latency chain — batch 4 records/lane (4 rtn-atomics in
// flight before the stores consume them) + 512-thread blocks (16 waves/CU,
// occ 22.5 -> ~50%). Predicted scatter 348 -> ~110-150us, total ~630-680us.

#define V 256
#define VOLSZ (V * V * V)              // 16,777,216
#define LOG2P 22
#define NPTS (3 << LOG2P)              // 12,582,912
#define NBLK 512                       // blocks for count/scatter
#define PPB (NPTS / NBLK)              // 24,576
#define TPB 512                        // threads for count/scatter
#define PITER (PPB / TPB)              // 48
#define NBINS 8192                     // 2 groups * 4096 cells (16^3 voxels)
#define NCPG 4096                      // cells per group: 16 x 16 x 16
// value tile logical shape: (x 17) x (y 17) x (z 17), x fastest
#define TX 17
#define TXY (TX * 17)                  // 289
#define TILE3 (TXY * 17)               // 4913 voxel values
#define HALO 817                       // 4913 - 16*16*16
// packed u64 tile: per (z,y) row 16 words = 8 A-pairs (base even) + 8 B-pairs (base odd)
#define TROW 16
#define TWORDS (289 * TROW)            // 4624 u64 = 36,992 B
#define FSCALE 8192.0f                 // 2^13 fixed-point scale
#define FBIAS 131072                   // 2^17 per-addend bias
#define FINV (1.0f / 8192.0f)

// workspace layout (bytes)
#define R_OFF 0ULL
#define R_BYTES (8ULL * NPTS)                       // packed records (100.7 MB)
#define P_OFF (R_OFF + R_BYTES)
#define P_BYTES (4ULL * NBLK * NBINS)               // per-block histograms (16.8 MB)
#define T_OFF (P_OFF + P_BYTES)
#define T_BYTES (4ULL * NBINS)
#define B_OFF (T_OFF + T_BYTES)
#define B_BYTES (4ULL * (NBINS + 1) + 28)
#define H_OFF (B_OFF + B_BYTES)
#define H_BYTES (2ULL * NBINS * HALO)               // f16 halo side buffer (13.4 MB)
#define WS_REQ (H_OFF + H_BYTES)                    // ~131 MB

// fixed-point: voxel coord * 2048 (11-bit fraction), 19 bits total.
// cell: 16-voxel in each dim -> cx = X>>15, cy = Y>>15, cz = Z>>15.
__device__ __forceinline__ void point_to_bin(float x, float y, float z,
                                             unsigned& X, unsigned& Y, unsigned& Z,
                                             int& cell) {
    float xf = (x + 1.f) * 127.5f;   // [0, 255]
    float yf = (y + 1.f) * 127.5f;
    float zf = (z + 1.f) * 127.5f;
    X = (unsigned)(int)(xf * 2048.0f);
    Y = (unsigned)(int)(yf * 2048.0f);
    Z = (unsigned)(int)(zf * 2048.0f);
    int cx = (int)(X >> 15), cy = (int)(Y >> 15), cz = (int)(Z >> 15);
    cell = (cz << 8) | (cy << 4) | cx;            // [0, 4096)
}

// ---------------- pass 1: per-block histogram ----------------
__global__ __launch_bounds__(TPB)
void count_k(const float* __restrict__ pts, unsigned* __restrict__ partials) {
    __shared__ unsigned hist[NBINS];
    for (int j = threadIdx.x; j < NBINS; j += TPB) hist[j] = 0u;
    __syncthreads();
    int b = blockIdx.x;
    long long base = (long long)b * PPB;
#pragma unroll 4
    for (int k = 0; k < PITER; ++k) {
        long long i = base + threadIdx.x + k * TPB;
        int view = (int)(i >> LOG2P);
        const float* pp = pts + i * 3;
        unsigned X, Y, Z; int cell;
        point_to_bin(pp[0], pp[1], pp[2], X, Y, Z, cell);
        int bin = ((view < 2) ? 0 : NCPG) + cell;
        atomicAdd(&hist[bin], 1u);
    }
    __syncthreads();
    for (int j = threadIdx.x; j < NBINS; j += TPB)
        partials[(size_t)b * NBINS + j] = hist[j];
}

// ---------------- pass 2a: bin totals ----------------
__global__ __launch_bounds__(256)
void totals_k(const unsigned* __restrict__ partials, unsigned* __restrict__ totals) {
    int bin = blockIdx.x * 256 + threadIdx.x;
    unsigned s = 0;
#pragma unroll 8
    for (int k = 0; k < NBLK; ++k) s += partials[(size_t)k * NBINS + bin];
    totals[bin] = s;
}

// ---------------- pass 2b: exclusive scan of totals -> bases[NBINS+1] ----------------
__global__ __launch_bounds__(1024)
void scan_k(const unsigned* __restrict__ totals, unsigned* __restrict__ bases) {
    __shared__ unsigned chunk[1024];
    int t = threadIdx.x;
    unsigned v[NBINS / 1024]; unsigned run = 0;
#pragma unroll
    for (int j = 0; j < NBINS / 1024; ++j) { v[j] = totals[t * (NBINS / 1024) + j]; run += v[j]; }
    chunk[t] = run;
    __syncthreads();
    for (int off = 1; off < 1024; off <<= 1) {
        unsigned add = (t >= off) ? chunk[t - off] : 0u;
        __syncthreads();
        chunk[t] += add;
        __syncthreads();
    }
    unsigned excl = (t == 0) ? 0u : chunk[t - 1];
    unsigned r = excl;
    if (t == 0) bases[0] = 0u;
#pragma unroll
    for (int j = 0; j < NBINS / 1024; ++j) { r += v[j]; bases[t * (NBINS / 1024) + 1 + j] = r; }
}

// ---------------- pass 2c: per-(block,bin) start offsets, in place ----------------
__global__ __launch_bounds__(256)
void offsets_k(unsigned* __restrict__ partials, const unsigned* __restrict__ bases) {
    int bin = blockIdx.x * 256 + threadIdx.x;
    unsigned run = bases[bin];
#pragma unroll 8
    for (int k = 0; k < NBLK; ++k) {
        unsigned c = partials[(size_t)k * NBINS + bin];
        partials[(size_t)k * NBINS + bin] = run;
        run += c;
    }
}

// ---------------- pass 3: scatter points into bin-sorted 8B records ----------------
// record: lo = lx15 | ly15<<15 | (Z&3)<<30 ; hi = (Z>>2)&0x1FFF | f16<<16
// Batched: 4 records per lane per outer iter -> 4 returning cursor atomics in
// flight before any store consumes a slot (breaks the rtn-atomic latency chain).
__global__ __launch_bounds__(TPB)
void scatter_k(const float* __restrict__ pts, const float* __restrict__ feat,
               const unsigned* __restrict__ offsets,
               unsigned long long* __restrict__ recs) {
    __shared__ unsigned cur[NBINS];
    int b = blockIdx.x;
    for (int j = threadIdx.x; j < NBINS; j += TPB)
        cur[j] = offsets[(size_t)b * NBINS + j];
    __syncthreads();
    long long base = (long long)b * PPB;
    for (int k = 0; k < PITER; k += 4) {
        unsigned slot[4];
        unsigned long long rec[4];
#pragma unroll
        for (int u = 0; u < 4; ++u) {
            long long i = base + threadIdx.x + (k + u) * TPB;
            int view = (int)(i >> LOG2P);
            const float* pp = pts + i * 3;
            unsigned X, Y, Z; int cell;
            point_to_bin(pp[0], pp[1], pp[2], X, Y, Z, cell);
            int bin = ((view < 2) ? 0 : NCPG) + cell;
            float wv = feat[i] * ((view < 2) ? 0.5f : 1.0f);
            unsigned hw = __half_as_ushort(__float2half(wv));
            unsigned lo = (X & 0x7FFFu) | ((Y & 0x7FFFu) << 15) | ((Z & 3u) << 30);
            unsigned hi = ((Z >> 2) & 0x1FFFu) | (hw << 16);
            rec[u] = (unsigned long long)lo | ((unsigned long long)hi << 32);
            slot[u] = atomicAdd(&cur[bin], 1u);
        }
#pragma unroll
        for (int u = 0; u < 4; ++u)
            recs[slot[u]] = rec[u];
    }
}

// ---------------- pass 4: per-cell splat via packed u64 fixed-point atomics ----------------
__device__ __forceinline__ void packadd(unsigned long long* p, float vlo, float vhi) {
    int elo = __float2int_rn(vlo * FSCALE) + FBIAS;
    int ehi = __float2int_rn(vhi * FSCALE) + FBIAS;
    unsigned long long add = ((unsigned long long)(unsigned)ehi << 37)
                           | ((unsigned long long)(unsigned)elo << 10) | 1ull;
    __hip_atomic_fetch_add(p, add, __ATOMIC_RELAXED, __HIP_MEMORY_SCOPE_WORKGROUP);
}

__device__ __forceinline__ void splat_rec(unsigned long long a, unsigned long long* t) {
    unsigned lo = (unsigned)a, hi = (unsigned)(a >> 32);
    unsigned lxf = lo & 0x7FFFu;                       // 4.11
    unsigned lyf = (lo >> 15) & 0x7FFFu;               // 4.11
    unsigned lzf = ((hi & 0x1FFFu) << 2) | (lo >> 30); // 4.11
    float w = __half2float(__ushort_as_half((unsigned short)(hi >> 16)));
    int lx = lxf >> 11, ly = lyf >> 11, lz = lzf >> 11;
    float fx = (lxf & 2047u) * (1.f / 2048.f);
    float fy = (lyf & 2047u) * (1.f / 2048.f);
    float fz = (lzf & 2047u) * (1.f / 2048.f);
    float wx0 = 1.f - fx, wy0 = 1.f - fy, wz0 = 1.f - fz;
    // word select: even lx -> A-word lx/2 (offset 0..7); odd lx -> B-word (lx-1)/2 (offset 8..15)
    int wsel = (lx >> 1) + ((lx & 1) << 3);
    int r00 = (lz * 17 + ly) * TROW + wsel;
    float w00 = w * wz0 * wy0, w01 = w * wz0 * fy;
    float w10 = w * fz * wy0,  w11 = w * fz * fy;
    packadd(&t[r00],                   w00 * wx0, w00 * fx);
    packadd(&t[r00 + TROW],            w01 * wx0, w01 * fx);
    packadd(&t[r00 + 17 * TROW],        w10 * wx0, w10 * fx);
    packadd(&t[r00 + 17 * TROW + TROW], w11 * wx0, w11 * fx);
}

__device__ __forceinline__ float decode_slot(unsigned long long w, bool hi_slot) {
    unsigned k = (unsigned)w & 1023u;
    unsigned f = hi_slot ? (unsigned)(w >> 37) : (unsigned)((w >> 10) & 0x07FFFFFFu);
    return ((int)f - (int)(k * (unsigned)FBIAS)) * FINV;
}

__global__ __launch_bounds__(256)
void splat_cells_k(const unsigned long long* __restrict__ recs,
                   const unsigned* __restrict__ bases,
                   float* __restrict__ out, __half* __restrict__ halo) {
    __shared__ unsigned long long tile[TWORDS];       // 36,992 B
    int bid = blockIdx.x;
    unsigned s = bases[bid], e = bases[bid + 1];
    // hoist first record load above the tile-zero phase (latency hides under it)
    unsigned i0 = s + threadIdx.x;
    unsigned long long pre = (i0 < e) ? recs[i0] : 0ull;

    for (int j = threadIdx.x; j < TWORDS; j += 256) tile[j] = 0ull;
    __syncthreads();

    if (i0 < e) {
        unsigned long long a = pre;
        for (unsigned i = i0 + 256; i < e; i += 256) {
            unsigned long long nxt = recs[i];   // next load in flight during splat
            splat_rec(a, tile);
            a = nxt;
        }
        splat_rec(a, tile);
    }
    __syncthreads();

    int g = bid >> 12, cc = bid & (NCPG - 1);
    int cx = cc & 15, cy = (cc >> 4) & 15, cz = cc >> 8;
    int ox = cx * 16, oy = cy * 16, oz = cz * 16;
    size_t obase = (size_t)g * VOLSZ;
    for (int idx = threadIdx.x; idx < TILE3; idx += 256) {
        int lz = idx / TXY;
        int r = idx - lz * TXY;
        int ly = r / TX;
        int lx = r - ly * TX;
        int rowb = (lz * 17 + ly) * TROW;
        float val = 0.f;
        if (lx < 16)   // A covers x 0..15: word x/2, slot = parity
            val += decode_slot(tile[rowb + (lx >> 1)], (lx & 1) != 0);
        if (lx >= 1)   // B covers x 1..16: word (x-1)/2, slot = !parity
            val += decode_slot(tile[rowb + 8 + ((lx - 1) >> 1)], (lx & 1) == 0);
        if (lx < 16 && ly < 16 && lz < 16) {
            out[obase + ((size_t)(oz + lz) * V + (oy + ly)) * V + (ox + lx)] = val;
        } else {
            int h;
            if (lx == 16)      h = ly * 17 + lz;              // 17*17 = 289
            else if (ly == 16) h = 289 + lx * 17 + lz;        // 16*17 = 272
            else               h = 561 + lx * 16 + ly;        // 16*16 = 256
            halo[(size_t)bid * HALO + h] = __float2half(val);
        }
    }
}

// ---------------- pass 5: add halo contributions on cell-boundary planes ----------------
__device__ __forceinline__ int hidx(int px, int py, int pz) {
    if (px == 16) return py * 17 + pz;
    if (py == 16) return 289 + px * 17 + pz;
    return 561 + px * 16 + py;
}

__global__ __launch_bounds__(256)
void halo_k(const __half* __restrict__ halo, float* __restrict__ out) {
    unsigned tid = blockIdx.x * 256 + threadIdx.x;   // 2^25 threads
    unsigned g = tid >> 24;
    unsigned v = tid & 0xFFFFFFu;
    int vx = v & 255, vy = (v >> 8) & 255, vz = v >> 16;
    int lx = vx & 15, ly = vy & 15, lz = vz & 15;
    int cx = vx >> 4, cy = vy >> 4, cz = vz >> 4;
    bool ax = (lx == 0) && (cx > 0);
    bool ay = (ly == 0) && (cy > 0);
    bool az = (lz == 0) && (cz > 0);
    if (!(ax || ay || az)) return;
    auto cellBase = [&](int ccx, int ccy, int ccz) {
        return (size_t)((g << 12) | (ccz << 8) | (ccy << 4) | ccx) * HALO;
    };
    float acc = 0.f;
    if (ax)             acc += __half2float(halo[cellBase(cx - 1, cy, cz) + hidx(16, ly, lz)]);
    if (ay)             acc += __half2float(halo[cellBase(cx, cy - 1, cz) + hidx(lx, 16, lz)]);
    if (az)             acc += __half2float(halo[cellBase(cx, cy, cz - 1) + hidx(lx, ly, 16)]);
    if (ax && ay)       acc += __half2float(halo[cellBase(cx - 1, cy - 1, cz) + hidx(16, 16, lz)]);
    if (ax && az)       acc += __half2float(halo[cellBase(cx - 1, cy, cz - 1) + hidx(16, ly, 16)]);
    if (ay && az)       acc += __half2float(halo[cellBase(cx, cy - 1, cz - 1) + hidx(lx, 16, 16)]);
    if (ax && ay && az) acc += __half2float(halo[cellBase(cx - 1, cy - 1, cz - 1) + hidx(16, 16, 16)]);
    out[(size_t)g * VOLSZ + v] += acc;
}

// ---------------- fallback (ws too small): direct atomic path ----------------
__global__ __launch_bounds__(256)
void zero_f4(float4* __restrict__ p, int n4) {
    int i = blockIdx.x * blockDim.x + threadIdx.x;
    if (i < n4) p[i] = make_float4(0.f, 0.f, 0.f, 0.f);
}

__global__ __launch_bounds__(256)
void splat_direct(const float* __restrict__ pts, const float* __restrict__ feat,
                  float* __restrict__ out) {
    int i = blockIdx.x * blockDim.x + threadIdx.x;
    if (i >= NPTS) return;
    int b = i >> LOG2P;
    const float* pp = pts + (long long)i * 3;
    float scale = (b < 2) ? 0.5f : 1.0f;
    float* dst = out + ((b < 2) ? 0 : VOLSZ);
    float xf = (pp[0] + 1.f) * 127.5f, yf = (pp[1] + 1.f) * 127.5f, zf = (pp[2] + 1.f) * 127.5f;
    float lxf = floorf(xf), lyf = floorf(yf), lzf = floorf(zf);
    float fx = xf - lxf, fy = yf - lyf, fz = zf - lzf;
    int ix = (int)lxf, iy = (int)lyf, iz = (int)lzf;
    float wv = feat[i] * scale;
    float wx[2] = {1.f - fx, fx}, wy[2] = {1.f - fy, fy}, wz[2] = {1.f - fz, fz};
#pragma unroll
    for (int dz = 0; dz < 2; ++dz) {
        int z2 = iz + dz; if ((unsigned)z2 >= (unsigned)V) continue;
#pragma unroll
        for (int dy = 0; dy < 2; ++dy) {
            int y2 = iy + dy; if ((unsigned)y2 >= (unsigned)V) continue;
            float wzy = wz[dz] * wy[dy] * wv;
            int base = (z2 * V + y2) * V;
#pragma unroll
            for (int dx = 0; dx < 2; ++dx) {
                int x2 = ix + dx; if ((unsigned)x2 >= (unsigned)V) continue;
                unsafeAtomicAdd(dst + base + x2, wzy * wx[dx]);
            }
        }
    }
}

extern "C" void kernel_launch(void* const* d_in, const int* in_sizes, int n_in,
                              void* d_out, int out_size, void* d_ws, size_t ws_size,
                              hipStream_t stream) {
    const float* pts  = (const float*)d_in[0];
    const float* feat = (const float*)d_in[1];
    float* out = (float*)d_out;

    if (ws_size < WS_REQ) {
        int n4 = out_size / 4;
        zero_f4<<<(n4 + 255) / 256, 256, 0, stream>>>((float4*)out, n4);
        splat_direct<<<(NPTS + 255) / 256, 256, 0, stream>>>(pts, feat, out);
        return;
    }

    char* ws = (char*)d_ws;
    unsigned long long* recs = (unsigned long long*)(ws + R_OFF);
    unsigned* partials       = (unsigned*)(ws + P_OFF);
    unsigned* totals         = (unsigned*)(ws + T_OFF);
    unsigned* bases          = (unsigned*)(ws + B_OFF);
    __half* halo             = (__half*)(ws + H_OFF);

    count_k  <<<NBLK, TPB, 0, stream>>>(pts, partials);
    totals_k <<<NBINS / 256, 256, 0, stream>>>(partials, totals);
    scan_k   <<<1, 1024, 0, stream>>>(totals, bases);
    offsets_k<<<NBINS / 256, 256, 0, stream>>>(partials, bases);
    scatter_k<<<NBLK, TPB, 0, stream>>>(pts, feat, partials, recs);
    splat_cells_k<<<NBINS, 256, 0, stream>>>(recs, bases, out, halo);
    halo_k   <<<(1u << 25) / 256, 256, 0, stream>>>(halo, out);
}

// Round 5
// 717.648 us; speedup vs baseline: 3.8692x; 1.0890x over previous
//
#include <hip/hip_runtime.h>
#include <hip/hip_fp16.h>

// NeRV trilinear splat, v8.
// v7 verdict: batch-4 cursor atomics helped (348->294us) but occupancy capped at
// 38% — grid is 512 blocks x 512thr = only 16 waves/CU. Still latency-starved:
// VALUBusy 4%, HBM 1.66TB/s (21%), far under the ~3.5-4TB/s pattern ceiling.
// v8: TPB 512->1024 for count/scatter (2 blocks/CU x 16 waves = 32 waves/CU,
// 100% occupancy; VGPR 20 fits 64-reg budget). halo_k: 4 voxels/thread (2^23
// threads instead of 2^25, 83% of which early-exited). Everything else frozen
// (v6 packed-u64 splat at its ~240us atomic-pipe floor).

#define V 256
#define VOLSZ (V * V * V)              // 16,777,216
#define LOG2P 22
#define NPTS (3 << LOG2P)              // 12,582,912
#define NBLK 512                       // blocks for count/scatter
#define PPB (NPTS / NBLK)              // 24,576
#define TPB 1024                       // threads for count/scatter
#define PITER (PPB / TPB)              // 24
#define NBINS 8192                     // 2 groups * 4096 cells (16^3 voxels)
#define NCPG 4096                      // cells per group: 16 x 16 x 16
// value tile logical shape: (x 17) x (y 17) x (z 17), x fastest
#define TX 17
#define TXY (TX * 17)                  // 289
#define TILE3 (TXY * 17)               // 4913 voxel values
#define HALO 817                       // 4913 - 16*16*16
// packed u64 tile: per (z,y) row 16 words = 8 A-pairs (base even) + 8 B-pairs (base odd)
#define TROW 16
#define TWORDS (289 * TROW)            // 4624 u64 = 36,992 B
#define FSCALE 8192.0f                 // 2^13 fixed-point scale
#define FBIAS 131072                   // 2^17 per-addend bias
#define FINV (1.0f / 8192.0f)

// workspace layout (bytes)
#define R_OFF 0ULL
#define R_BYTES (8ULL * NPTS)                       // packed records (100.7 MB)
#define P_OFF (R_OFF + R_BYTES)
#define P_BYTES (4ULL * NBLK * NBINS)               // per-block histograms (16.8 MB)
#define T_OFF (P_OFF + P_BYTES)
#define T_BYTES (4ULL * NBINS)
#define B_OFF (T_OFF + T_BYTES)
#define B_BYTES (4ULL * (NBINS + 1) + 28)
#define H_OFF (B_OFF + B_BYTES)
#define H_BYTES (2ULL * NBINS * HALO)               // f16 halo side buffer (13.4 MB)
#define WS_REQ (H_OFF + H_BYTES)                    // ~131 MB

// fixed-point: voxel coord * 2048 (11-bit fraction), 19 bits total.
// cell: 16-voxel in each dim -> cx = X>>15, cy = Y>>15, cz = Z>>15.
__device__ __forceinline__ void point_to_bin(float x, float y, float z,
                                             unsigned& X, unsigned& Y, unsigned& Z,
                                             int& cell) {
    float xf = (x + 1.f) * 127.5f;   // [0, 255]
    float yf = (y + 1.f) * 127.5f;
    float zf = (z + 1.f) * 127.5f;
    X = (unsigned)(int)(xf * 2048.0f);
    Y = (unsigned)(int)(yf * 2048.0f);
    Z = (unsigned)(int)(zf * 2048.0f);
    int cx = (int)(X >> 15), cy = (int)(Y >> 15), cz = (int)(Z >> 15);
    cell = (cz << 8) | (cy << 4) | cx;            // [0, 4096)
}

// ---------------- pass 1: per-block histogram ----------------
__global__ __launch_bounds__(TPB)
void count_k(const float* __restrict__ pts, unsigned* __restrict__ partials) {
    __shared__ unsigned hist[NBINS];
    for (int j = threadIdx.x; j < NBINS; j += TPB) hist[j] = 0u;
    __syncthreads();
    int b = blockIdx.x;
    long long base = (long long)b * PPB;
#pragma unroll 4
    for (int k = 0; k < PITER; ++k) {
        long long i = base + threadIdx.x + k * TPB;
        int view = (int)(i >> LOG2P);
        const float* pp = pts + i * 3;
        unsigned X, Y, Z; int cell;
        point_to_bin(pp[0], pp[1], pp[2], X, Y, Z, cell);
        int bin = ((view < 2) ? 0 : NCPG) + cell;
        atomicAdd(&hist[bin], 1u);
    }
    __syncthreads();
    for (int j = threadIdx.x; j < NBINS; j += TPB)
        partials[(size_t)b * NBINS + j] = hist[j];
}

// ---------------- pass 2a: bin totals ----------------
__global__ __launch_bounds__(256)
void totals_k(const unsigned* __restrict__ partials, unsigned* __restrict__ totals) {
    int bin = blockIdx.x * 256 + threadIdx.x;
    unsigned s = 0;
#pragma unroll 8
    for (int k = 0; k < NBLK; ++k) s += partials[(size_t)k * NBINS + bin];
    totals[bin] = s;
}

// ---------------- pass 2b: exclusive scan of totals -> bases[NBINS+1] ----------------
__global__ __launch_bounds__(1024)
void scan_k(const unsigned* __restrict__ totals, unsigned* __restrict__ bases) {
    __shared__ unsigned chunk[1024];
    int t = threadIdx.x;
    unsigned v[NBINS / 1024]; unsigned run = 0;
#pragma unroll
    for (int j = 0; j < NBINS / 1024; ++j) { v[j] = totals[t * (NBINS / 1024) + j]; run += v[j]; }
    chunk[t] = run;
    __syncthreads();
    for (int off = 1; off < 1024; off <<= 1) {
        unsigned add = (t >= off) ? chunk[t - off] : 0u;
        __syncthreads();
        chunk[t] += add;
        __syncthreads();
    }
    unsigned excl = (t == 0) ? 0u : chunk[t - 1];
    unsigned r = excl;
    if (t == 0) bases[0] = 0u;
#pragma unroll
    for (int j = 0; j < NBINS / 1024; ++j) { r += v[j]; bases[t * (NBINS / 1024) + 1 + j] = r; }
}

// ---------------- pass 2c: per-(block,bin) start offsets, in place ----------------
__global__ __launch_bounds__(256)
void offsets_k(unsigned* __restrict__ partials, const unsigned* __restrict__ bases) {
    int bin = blockIdx.x * 256 + threadIdx.x;
    unsigned run = bases[bin];
#pragma unroll 8
    for (int k = 0; k < NBLK; ++k) {
        unsigned c = partials[(size_t)k * NBINS + bin];
        partials[(size_t)k * NBINS + bin] = run;
        run += c;
    }
}

// ---------------- pass 3: scatter points into bin-sorted 8B records ----------------
// record: lo = lx15 | ly15<<15 | (Z&3)<<30 ; hi = (Z>>2)&0x1FFF | f16<<16
// Batched: 4 records per lane per outer iter -> 4 returning cursor atomics in
// flight before any store consumes a slot (breaks the rtn-atomic latency chain).
__global__ __launch_bounds__(TPB)
void scatter_k(const float* __restrict__ pts, const float* __restrict__ feat,
               const unsigned* __restrict__ offsets,
               unsigned long long* __restrict__ recs) {
    __shared__ unsigned cur[NBINS];
    int b = blockIdx.x;
    for (int j = threadIdx.x; j < NBINS; j += TPB)
        cur[j] = offsets[(size_t)b * NBINS + j];
    __syncthreads();
    long long base = (long long)b * PPB;
    for (int k = 0; k < PITER; k += 4) {
        unsigned slot[4];
        unsigned long long rec[4];
#pragma unroll
        for (int u = 0; u < 4; ++u) {
            long long i = base + threadIdx.x + (k + u) * TPB;
            int view = (int)(i >> LOG2P);
            const float* pp = pts + i * 3;
            unsigned X, Y, Z; int cell;
            point_to_bin(pp[0], pp[1], pp[2], X, Y, Z, cell);
            int bin = ((view < 2) ? 0 : NCPG) + cell;
            float wv = feat[i] * ((view < 2) ? 0.5f : 1.0f);
            unsigned hw = __half_as_ushort(__float2half(wv));
            unsigned lo = (X & 0x7FFFu) | ((Y & 0x7FFFu) << 15) | ((Z & 3u) << 30);
            unsigned hi = ((Z >> 2) & 0x1FFFu) | (hw << 16);
            rec[u] = (unsigned long long)lo | ((unsigned long long)hi << 32);
            slot[u] = atomicAdd(&cur[bin], 1u);
        }
#pragma unroll
        for (int u = 0; u < 4; ++u)
            recs[slot[u]] = rec[u];
    }
}

// ---------------- pass 4: per-cell splat via packed u64 fixed-point atomics ----------------
__device__ __forceinline__ void packadd(unsigned long long* p, float vlo, float vhi) {
    int elo = __float2int_rn(vlo * FSCALE) + FBIAS;
    int ehi = __float2int_rn(vhi * FSCALE) + FBIAS;
    unsigned long long add = ((unsigned long long)(unsigned)ehi << 37)
                           | ((unsigned long long)(unsigned)elo << 10) | 1ull;
    __hip_atomic_fetch_add(p, add, __ATOMIC_RELAXED, __HIP_MEMORY_SCOPE_WORKGROUP);
}

__device__ __forceinline__ void splat_rec(unsigned long long a, unsigned long long* t) {
    unsigned lo = (unsigned)a, hi = (unsigned)(a >> 32);
    unsigned lxf = lo & 0x7FFFu;                       // 4.11
    unsigned lyf = (lo >> 15) & 0x7FFFu;               // 4.11
    unsigned lzf = ((hi & 0x1FFFu) << 2) | (lo >> 30); // 4.11
    float w = __half2float(__ushort_as_half((unsigned short)(hi >> 16)));
    int lx = lxf >> 11, ly = lyf >> 11, lz = lzf >> 11;
    float fx = (lxf & 2047u) * (1.f / 2048.f);
    float fy = (lyf & 2047u) * (1.f / 2048.f);
    float fz = (lzf & 2047u) * (1.f / 2048.f);
    float wx0 = 1.f - fx, wy0 = 1.f - fy, wz0 = 1.f - fz;
    // word select: even lx -> A-word lx/2 (offset 0..7); odd lx -> B-word (lx-1)/2 (offset 8..15)
    int wsel = (lx >> 1) + ((lx & 1) << 3);
    int r00 = (lz * 17 + ly) * TROW + wsel;
    float w00 = w * wz0 * wy0, w01 = w * wz0 * fy;
    float w10 = w * fz * wy0,  w11 = w * fz * fy;
    packadd(&t[r00],                   w00 * wx0, w00 * fx);
    packadd(&t[r00 + TROW],            w01 * wx0, w01 * fx);
    packadd(&t[r00 + 17 * TROW],        w10 * wx0, w10 * fx);
    packadd(&t[r00 + 17 * TROW + TROW], w11 * wx0, w11 * fx);
}

__device__ __forceinline__ float decode_slot(unsigned long long w, bool hi_slot) {
    unsigned k = (unsigned)w & 1023u;
    unsigned f = hi_slot ? (unsigned)(w >> 37) : (unsigned)((w >> 10) & 0x07FFFFFFu);
    return ((int)f - (int)(k * (unsigned)FBIAS)) * FINV;
}

__global__ __launch_bounds__(256)
void splat_cells_k(const unsigned long long* __restrict__ recs,
                   const unsigned* __restrict__ bases,
                   float* __restrict__ out, __half* __restrict__ halo) {
    __shared__ unsigned long long tile[TWORDS];       // 36,992 B
    int bid = blockIdx.x;
    unsigned s = bases[bid], e = bases[bid + 1];
    // hoist first record load above the tile-zero phase (latency hides under it)
    unsigned i0 = s + threadIdx.x;
    unsigned long long pre = (i0 < e) ? recs[i0] : 0ull;

    for (int j = threadIdx.x; j < TWORDS; j += 256) tile[j] = 0ull;
    __syncthreads();

    if (i0 < e) {
        unsigned long long a = pre;
        for (unsigned i = i0 + 256; i < e; i += 256) {
            unsigned long long nxt = recs[i];   // next load in flight during splat
            splat_rec(a, tile);
            a = nxt;
        }
        splat_rec(a, tile);
    }
    __syncthreads();

    int g = bid >> 12, cc = bid & (NCPG - 1);
    int cx = cc & 15, cy = (cc >> 4) & 15, cz = cc >> 8;
    int ox = cx * 16, oy = cy * 16, oz = cz * 16;
    size_t obase = (size_t)g * VOLSZ;
    for (int idx = threadIdx.x; idx < TILE3; idx += 256) {
        int lz = idx / TXY;
        int r = idx - lz * TXY;
        int ly = r / TX;
        int lx = r - ly * TX;
        int rowb = (lz * 17 + ly) * TROW;
        float val = 0.f;
        if (lx < 16)   // A covers x 0..15: word x/2, slot = parity
            val += decode_slot(tile[rowb + (lx >> 1)], (lx & 1) != 0);
        if (lx >= 1)   // B covers x 1..16: word (x-1)/2, slot = !parity
            val += decode_slot(tile[rowb + 8 + ((lx - 1) >> 1)], (lx & 1) == 0);
        if (lx < 16 && ly < 16 && lz < 16) {
            out[obase + ((size_t)(oz + lz) * V + (oy + ly)) * V + (ox + lx)] = val;
        } else {
            int h;
            if (lx == 16)      h = ly * 17 + lz;              // 17*17 = 289
            else if (ly == 16) h = 289 + lx * 17 + lz;        // 16*17 = 272
            else               h = 561 + lx * 16 + ly;        // 16*16 = 256
            halo[(size_t)bid * HALO + h] = __float2half(val);
        }
    }
}

// ---------------- pass 5: add halo contributions on cell-boundary planes ----------------
__device__ __forceinline__ int hidx(int px, int py, int pz) {
    if (px == 16) return py * 17 + pz;
    if (py == 16) return 289 + px * 17 + pz;
    return 561 + px * 16 + py;
}

// 4 x-consecutive voxels per thread: 2^23 threads (was 2^25 with 83% early-exit)
__global__ __launch_bounds__(256)
void halo_k(const __half* __restrict__ halo, float* __restrict__ out) {
    unsigned tid = blockIdx.x * 256 + threadIdx.x;   // 2^23 threads
    unsigned g = tid >> 22;
    unsigned v = (tid & 0x3FFFFFu) << 2;             // base voxel, vx multiple of 4
    int vx = v & 255, vy = (v >> 8) & 255, vz = v >> 16;
    int ly = vy & 15, lz = vz & 15;
    int cy = vy >> 4, cz = vz >> 4;
    bool ay = (ly == 0) && (cy > 0);
    bool az = (lz == 0) && (cz > 0);
    bool ax0 = ((vx & 15) == 0) && (vx >= 16);       // lx==0 && cx>0 at j=0
    if (!(ax0 || ay || az)) return;
    auto cellBase = [&](int ccx, int ccy, int ccz) {
        return (size_t)((g << 12) | (ccz << 8) | (ccy << 4) | ccx) * HALO;
    };
    size_t obase = (size_t)g * VOLSZ + v;
#pragma unroll
    for (int j = 0; j < 4; ++j) {
        int x = vx + j;
        int lx = x & 15, cx = x >> 4;
        bool ax = (j == 0) && ax0;
        if (!(ax || ay || az)) continue;
        float acc = 0.f;
        if (ax)             acc += __half2float(halo[cellBase(cx - 1, cy, cz) + hidx(16, ly, lz)]);
        if (ay)             acc += __half2float(halo[cellBase(cx, cy - 1, cz) + hidx(lx, 16, lz)]);
        if (az)             acc += __half2float(halo[cellBase(cx, cy, cz - 1) + hidx(lx, ly, 16)]);
        if (ax && ay)       acc += __half2float(halo[cellBase(cx - 1, cy - 1, cz) + hidx(16, 16, lz)]);
        if (ax && az)       acc += __half2float(halo[cellBase(cx - 1, cy, cz - 1) + hidx(16, ly, 16)]);
        if (ay && az)       acc += __half2float(halo[cellBase(cx, cy - 1, cz - 1) + hidx(lx, 16, 16)]);
        if (ax && ay && az) acc += __half2float(halo[cellBase(cx - 1, cy - 1, cz - 1) + hidx(16, 16, 16)]);
        out[obase + j] += acc;
    }
}

// ---------------- fallback (ws too small): direct atomic path ----------------
__global__ __launch_bounds__(256)
void zero_f4(float4* __restrict__ p, int n4) {
    int i = blockIdx.x * blockDim.x + threadIdx.x;
    if (i < n4) p[i] = make_float4(0.f, 0.f, 0.f, 0.f);
}

__global__ __launch_bounds__(256)
void splat_direct(const float* __restrict__ pts, const float* __restrict__ feat,
                  float* __restrict__ out) {
    int i = blockIdx.x * blockDim.x + threadIdx.x;
    if (i >= NPTS) return;
    int b = i >> LOG2P;
    const float* pp = pts + (long long)i * 3;
    float scale = (b < 2) ? 0.5f : 1.0f;
    float* dst = out + ((b < 2) ? 0 : VOLSZ);
    float xf = (pp[0] + 1.f) * 127.5f, yf = (pp[1] + 1.f) * 127.5f, zf = (pp[2] + 1.f) * 127.5f;
    float lxf = floorf(xf), lyf = floorf(yf), lzf = floorf(zf);
    float fx = xf - lxf, fy = yf - lyf, fz = zf - lzf;
    int ix = (int)lxf, iy = (int)lyf, iz = (int)lzf;
    float wv = feat[i] * scale;
    float wx[2] = {1.f - fx, fx}, wy[2] = {1.f - fy, fy}, wz[2] = {1.f - fz, fz};
#pragma unroll
    for (int dz = 0; dz < 2; ++dz) {
        int z2 = iz + dz; if ((unsigned)z2 >= (unsigned)V) continue;
#pragma unroll
        for (int dy = 0; dy < 2; ++dy) {
            int y2 = iy + dy; if ((unsigned)y2 >= (unsigned)V) continue;
            float wzy = wz[dz] * wy[dy] * wv;
            int base = (z2 * V + y2) * V;
#pragma unroll
            for (int dx = 0; dx < 2; ++dx) {
                int x2 = ix + dx; if ((unsigned)x2 >= (unsigned)V) continue;
                unsafeAtomicAdd(dst + base + x2, wzy * wx[dx]);
            }
        }
    }
}

extern "C" void kernel_launch(void* const* d_in, const int* in_sizes, int n_in,
                              void* d_out, int out_size, void* d_ws, size_t ws_size,
                              hipStream_t stream) {
    const float* pts  = (const float*)d_in[0];
    const float* feat = (const float*)d_in[1];
    float* out = (float*)d_out;

    if (ws_size < WS_REQ) {
        int n4 = out_size / 4;
        zero_f4<<<(n4 + 255) / 256, 256, 0, stream>>>((float4*)out, n4);
        splat_direct<<<(NPTS + 255) / 256, 256, 0, stream>>>(pts, feat, out);
        return;
    }

    char* ws = (char*)d_ws;
    unsigned long long* recs = (unsigned long long*)(ws + R_OFF);
    unsigned* partials       = (unsigned*)(ws + P_OFF);
    unsigned* totals         = (unsigned*)(ws + T_OFF);
    unsigned* bases          = (unsigned*)(ws + B_OFF);
    __half* halo             = (__half*)(ws + H_OFF);

    count_k  <<<NBLK, TPB, 0, stream>>>(pts, partials);
    totals_k <<<NBINS / 256, 256, 0, stream>>>(partials, totals);
    scan_k   <<<1, 1024, 0, stream>>>(totals, bases);
    offsets_k<<<NBINS / 256, 256, 0, stream>>>(partials, bases);
    scatter_k<<<NBLK, TPB, 0, stream>>>(pts, feat, partials, recs);
    splat_cells_k<<<NBINS, 256, 0, stream>>>(recs, bases, out, halo);
    halo_k   <<<(1u << 23) / 256, 256, 0, stream>>>(halo, out);
}

// Round 6
// 684.803 us; speedup vs baseline: 4.0548x; 1.0480x over previous
//
#include <hip/hip_runtime.h>
#include <hip/hip_fp16.h>

// NeRV trilinear splat, v9.
// v8 verdict: occupancy lever exhausted (scatter 294->264us, 61% occ). Scatter is
// now partial-sector-RMW bound: write model 512blk x 8192bins = 4.2M runs x 24B
// -> 366MB predicted vs 371MB measured WRITE_SIZE. v9: halve bins (cells 32x16x16,
// v3 geometry, 4096 bins) -> runs 48B -> ~232MB predicted. Splat keeps the v6
// packed-u64 atomic scheme (4 ops/record, pipe floor ~240us); tile grows to
// 9248 u64 = 74KB -> dynamic LDS + hipFuncSetAttribute (512thr x 2blk/CU = 16
// waves, same as v6). Record packing + halo layout lifted from proven v3.

#define V 256
#define VOLSZ (V * V * V)              // 16,777,216
#define LOG2P 22
#define NPTS (3 << LOG2P)              // 12,582,912
#define NBLK 512                       // blocks for count/scatter
#define PPB (NPTS / NBLK)              // 24,576
#define TPB 1024                       // threads for count/scatter
#define PITER (PPB / TPB)              // 24
#define NBINS 4096                     // 2 groups * 2048 cells (32x16x16 voxels)
#define NCPG 2048                      // cells per group: 8 x 16 x 16
// value tile logical shape: (x 33) x (y 17) x (z 17), x fastest
#define TX 33
#define TXY (TX * 17)                  // 561
#define TILE3 (TXY * 17)               // 9537 voxel values
#define HALO 1345                      // 9537 - 32*16*16
// packed u64 tile: per (z,y) row 32 words = 16 A-pairs (base even) + 16 B-pairs (base odd)
#define TROW 32
#define TWORDS (289 * TROW)            // 9248 u64 = 73,984 B  (dynamic LDS)
#define STPB 512                       // threads for splat
#define FSCALE 8192.0f                 // 2^13 fixed-point scale
#define FBIAS 131072                   // 2^17 per-addend bias
#define FINV (1.0f / 8192.0f)

// workspace layout (bytes)
#define R_OFF 0ULL
#define R_BYTES (8ULL * NPTS)                       // packed records (100.7 MB)
#define P_OFF (R_OFF + R_BYTES)
#define P_BYTES (4ULL * NBLK * NBINS)               // per-block histograms (8.4 MB)
#define T_OFF (P_OFF + P_BYTES)
#define T_BYTES (4ULL * NBINS)
#define B_OFF (T_OFF + T_BYTES)
#define B_BYTES (4ULL * (NBINS + 1) + 28)
#define H_OFF (B_OFF + B_BYTES)
#define H_BYTES (2ULL * NBINS * HALO)               // f16 halo side buffer (11.0 MB)
#define WS_REQ (H_OFF + H_BYTES)                    // ~120 MB

// fixed-point: voxel coord * 2048 (11-bit fraction), 19 bits total.
// cell: 32-voxel x -> cx = X>>16; 16-voxel y,z -> cy = Y>>15, cz = Z>>15.
__device__ __forceinline__ void point_to_bin(float x, float y, float z,
                                             unsigned& X, unsigned& Y, unsigned& Z,
                                             int& cell) {
    float xf = (x + 1.f) * 127.5f;   // [0, 255]
    float yf = (y + 1.f) * 127.5f;
    float zf = (z + 1.f) * 127.5f;
    X = (unsigned)(int)(xf * 2048.0f);
    Y = (unsigned)(int)(yf * 2048.0f);
    Z = (unsigned)(int)(zf * 2048.0f);
    int cx = (int)(X >> 16), cy = (int)(Y >> 15), cz = (int)(Z >> 15);
    cell = (cz << 7) | (cy << 3) | cx;            // [0, 2048)
}

// ---------------- pass 1: per-block histogram ----------------
__global__ __launch_bounds__(TPB)
void count_k(const float* __restrict__ pts, unsigned* __restrict__ partials) {
    __shared__ unsigned hist[NBINS];
    for (int j = threadIdx.x; j < NBINS; j += TPB) hist[j] = 0u;
    __syncthreads();
    int b = blockIdx.x;
    long long base = (long long)b * PPB;
#pragma unroll 4
    for (int k = 0; k < PITER; ++k) {
        long long i = base + threadIdx.x + k * TPB;
        int view = (int)(i >> LOG2P);
        const float* pp = pts + i * 3;
        unsigned X, Y, Z; int cell;
        point_to_bin(pp[0], pp[1], pp[2], X, Y, Z, cell);
        int bin = ((view < 2) ? 0 : NCPG) + cell;
        atomicAdd(&hist[bin], 1u);
    }
    __syncthreads();
    for (int j = threadIdx.x; j < NBINS; j += TPB)
        partials[(size_t)b * NBINS + j] = hist[j];
}

// ---------------- pass 2a: bin totals ----------------
__global__ __launch_bounds__(256)
void totals_k(const unsigned* __restrict__ partials, unsigned* __restrict__ totals) {
    int bin = blockIdx.x * 256 + threadIdx.x;
    unsigned s = 0;
#pragma unroll 8
    for (int k = 0; k < NBLK; ++k) s += partials[(size_t)k * NBINS + bin];
    totals[bin] = s;
}

// ---------------- pass 2b: exclusive scan of totals -> bases[NBINS+1] ----------------
__global__ __launch_bounds__(1024)
void scan_k(const unsigned* __restrict__ totals, unsigned* __restrict__ bases) {
    __shared__ unsigned chunk[1024];
    int t = threadIdx.x;
    unsigned v[NBINS / 1024]; unsigned run = 0;
#pragma unroll
    for (int j = 0; j < NBINS / 1024; ++j) { v[j] = totals[t * (NBINS / 1024) + j]; run += v[j]; }
    chunk[t] = run;
    __syncthreads();
    for (int off = 1; off < 1024; off <<= 1) {
        unsigned add = (t >= off) ? chunk[t - off] : 0u;
        __syncthreads();
        chunk[t] += add;
        __syncthreads();
    }
    unsigned excl = (t == 0) ? 0u : chunk[t - 1];
    unsigned r = excl;
    if (t == 0) bases[0] = 0u;
#pragma unroll
    for (int j = 0; j < NBINS / 1024; ++j) { r += v[j]; bases[t * (NBINS / 1024) + 1 + j] = r; }
}

// ---------------- pass 2c: per-(block,bin) start offsets, in place ----------------
__global__ __launch_bounds__(256)
void offsets_k(unsigned* __restrict__ partials, const unsigned* __restrict__ bases) {
    int bin = blockIdx.x * 256 + threadIdx.x;
    unsigned run = bases[bin];
#pragma unroll 8
    for (int k = 0; k < NBLK; ++k) {
        unsigned c = partials[(size_t)k * NBINS + bin];
        partials[(size_t)k * NBINS + bin] = run;
        run += c;
    }
}

// ---------------- pass 3: scatter points into bin-sorted 8B records ----------------
// record (v3 packing): lo = lx16 | ly15<<16 ; hi = lz15 | f16<<16
// Batched: 4 records per lane -> 4 returning cursor atomics in flight.
__global__ __launch_bounds__(TPB)
void scatter_k(const float* __restrict__ pts, const float* __restrict__ feat,
               const unsigned* __restrict__ offsets,
               unsigned long long* __restrict__ recs) {
    __shared__ unsigned cur[NBINS];
    int b = blockIdx.x;
    for (int j = threadIdx.x; j < NBINS; j += TPB)
        cur[j] = offsets[(size_t)b * NBINS + j];
    __syncthreads();
    long long base = (long long)b * PPB;
    for (int k = 0; k < PITER; k += 4) {
        unsigned slot[4];
        unsigned long long rec[4];
#pragma unroll
        for (int u = 0; u < 4; ++u) {
            long long i = base + threadIdx.x + (k + u) * TPB;
            int view = (int)(i >> LOG2P);
            const float* pp = pts + i * 3;
            unsigned X, Y, Z; int cell;
            point_to_bin(pp[0], pp[1], pp[2], X, Y, Z, cell);
            int bin = ((view < 2) ? 0 : NCPG) + cell;
            float wv = feat[i] * ((view < 2) ? 0.5f : 1.0f);
            unsigned hw = __half_as_ushort(__float2half(wv));
            unsigned lo = (X & 0xFFFFu) | ((Y & 0x7FFFu) << 16);
            unsigned hi = (Z & 0x7FFFu) | (hw << 16);
            rec[u] = (unsigned long long)lo | ((unsigned long long)hi << 32);
            slot[u] = atomicAdd(&cur[bin], 1u);
        }
#pragma unroll
        for (int u = 0; u < 4; ++u)
            recs[slot[u]] = rec[u];
    }
}

// ---------------- pass 4: per-cell splat via packed u64 fixed-point atomics ----------------
__device__ __forceinline__ void packadd(unsigned long long* p, float vlo, float vhi) {
    int elo = __float2int_rn(vlo * FSCALE) + FBIAS;
    int ehi = __float2int_rn(vhi * FSCALE) + FBIAS;
    unsigned long long add = ((unsigned long long)(unsigned)ehi << 37)
                           | ((unsigned long long)(unsigned)elo << 10) | 1ull;
    __hip_atomic_fetch_add(p, add, __ATOMIC_RELAXED, __HIP_MEMORY_SCOPE_WORKGROUP);
}

__device__ __forceinline__ void splat_rec(unsigned long long a, unsigned long long* t) {
    unsigned lo = (unsigned)a, hi = (unsigned)(a >> 32);
    unsigned lxf = lo & 0xFFFFu;            // 5.11
    unsigned lyf = (lo >> 16) & 0x7FFFu;    // 4.11
    unsigned lzf = hi & 0x7FFFu;            // 4.11
    float w = __half2float(__ushort_as_half((unsigned short)(hi >> 16)));
    int lx = lxf >> 11, ly = lyf >> 11, lz = lzf >> 11;
    float fx = (lxf & 2047u) * (1.f / 2048.f);
    float fy = (lyf & 2047u) * (1.f / 2048.f);
    float fz = (lzf & 2047u) * (1.f / 2048.f);
    float wx0 = 1.f - fx, wy0 = 1.f - fy, wz0 = 1.f - fz;
    // word select: even lx -> A-word lx/2 (0..15); odd lx -> B-word (lx-1)/2 + 16
    int wsel = (lx >> 1) + ((lx & 1) << 4);
    int r00 = (lz * 17 + ly) * TROW + wsel;
    float w00 = w * wz0 * wy0, w01 = w * wz0 * fy;
    float w10 = w * fz * wy0,  w11 = w * fz * fy;
    packadd(&t[r00],                    w00 * wx0, w00 * fx);
    packadd(&t[r00 + TROW],             w01 * wx0, w01 * fx);
    packadd(&t[r00 + 17 * TROW],        w10 * wx0, w10 * fx);
    packadd(&t[r00 + 17 * TROW + TROW], w11 * wx0, w11 * fx);
}

__device__ __forceinline__ float decode_slot(unsigned long long w, bool hi_slot) {
    unsigned k = (unsigned)w & 1023u;
    unsigned f = hi_slot ? (unsigned)(w >> 37) : (unsigned)((w >> 10) & 0x07FFFFFFu);
    return ((int)f - (int)(k * (unsigned)FBIAS)) * FINV;
}

__global__ __launch_bounds__(STPB)
void splat_cells_k(const unsigned long long* __restrict__ recs,
                   const unsigned* __restrict__ bases,
                   float* __restrict__ out, __half* __restrict__ halo) {
    extern __shared__ unsigned long long tile[];      // TWORDS u64 = 73,984 B
    int bid = blockIdx.x;
    unsigned s = bases[bid], e = bases[bid + 1];
    // hoist first record load above the tile-zero phase (latency hides under it)
    unsigned i0 = s + threadIdx.x;
    unsigned long long pre = (i0 < e) ? recs[i0] : 0ull;

    for (int j = threadIdx.x; j < TWORDS; j += STPB) tile[j] = 0ull;
    __syncthreads();

    if (i0 < e) {
        unsigned long long a = pre;
        for (unsigned i = i0 + STPB; i < e; i += STPB) {
            unsigned long long nxt = recs[i];   // next load in flight during splat
            splat_rec(a, tile);
            a = nxt;
        }
        splat_rec(a, tile);
    }
    __syncthreads();

    int g = bid >> 11, cc = bid & (NCPG - 1);
    int cx = cc & 7, cy = (cc >> 3) & 15, cz = cc >> 7;
    int ox = cx * 32, oy = cy * 16, oz = cz * 16;
    size_t obase = (size_t)g * VOLSZ;
    for (int idx = threadIdx.x; idx < TILE3; idx += STPB) {
        int lz = idx / TXY;
        int r = idx - lz * TXY;
        int ly = r / TX;
        int lx = r - ly * TX;
        int rowb = (lz * 17 + ly) * TROW;
        float val = 0.f;
        if (lx < 32)   // A covers x 0..31: word x/2, slot = parity
            val += decode_slot(tile[rowb + (lx >> 1)], (lx & 1) != 0);
        if (lx >= 1)   // B covers x 1..32: word 16 + (x-1)/2, slot = !parity
            val += decode_slot(tile[rowb + 16 + ((lx - 1) >> 1)], (lx & 1) == 0);
        if (lx < 32 && ly < 16 && lz < 16) {
            out[obase + ((size_t)(oz + lz) * V + (oy + ly)) * V + (ox + lx)] = val;
        } else {
            int h;
            if (lx == 32)      h = ly * 17 + lz;              // 17*17 = 289
            else if (ly == 16) h = 289 + lx * 17 + lz;        // 32*17 = 544
            else               h = 833 + lx * 16 + ly;        // 32*16 = 512
            halo[(size_t)bid * HALO + h] = __float2half(val);
        }
    }
}

// ---------------- pass 5: add halo contributions on cell-boundary planes ----------------
__device__ __forceinline__ int hidx(int px, int py, int pz) {
    if (px == 32) return py * 17 + pz;
    if (py == 16) return 289 + px * 17 + pz;
    return 833 + px * 16 + py;
}

// 4 x-consecutive voxels per thread: 2^23 threads
__global__ __launch_bounds__(256)
void halo_k(const __half* __restrict__ halo, float* __restrict__ out) {
    unsigned tid = blockIdx.x * 256 + threadIdx.x;   // 2^23 threads
    unsigned g = tid >> 22;
    unsigned v = (tid & 0x3FFFFFu) << 2;             // base voxel, vx multiple of 4
    int vx = v & 255, vy = (v >> 8) & 255, vz = v >> 16;
    int ly = vy & 15, lz = vz & 15;
    int cy = vy >> 4, cz = vz >> 4;
    bool ay = (ly == 0) && (cy > 0);
    bool az = (lz == 0) && (cz > 0);
    bool ax0 = ((vx & 31) == 0) && (vx >= 32);       // lx==0 && cx>0 possible only at j=0
    if (!(ax0 || ay || az)) return;
    auto cellBase = [&](int ccx, int ccy, int ccz) {
        return (size_t)((g << 11) | (ccz << 7) | (ccy << 3) | ccx) * HALO;
    };
    size_t obase = (size_t)g * VOLSZ + v;
#pragma unroll
    for (int j = 0; j < 4; ++j) {
        int x = vx + j;
        int lx = x & 31, cx = x >> 5;
        bool ax = (j == 0) && ax0;
        if (!(ax || ay || az)) continue;
        float acc = 0.f;
        if (ax)             acc += __half2float(halo[cellBase(cx - 1, cy, cz) + hidx(32, ly, lz)]);
        if (ay)             acc += __half2float(halo[cellBase(cx, cy - 1, cz) + hidx(lx, 16, lz)]);
        if (az)             acc += __half2float(halo[cellBase(cx, cy, cz - 1) + hidx(lx, ly, 16)]);
        if (ax && ay)       acc += __half2float(halo[cellBase(cx - 1, cy - 1, cz) + hidx(32, 16, lz)]);
        if (ax && az)       acc += __half2float(halo[cellBase(cx - 1, cy, cz - 1) + hidx(32, ly, 16)]);
        if (ay && az)       acc += __half2float(halo[cellBase(cx, cy - 1, cz - 1) + hidx(lx, 16, 16)]);
        if (ax && ay && az) acc += __half2float(halo[cellBase(cx - 1, cy - 1, cz - 1) + hidx(32, 16, 16)]);
        out[obase + j] += acc;
    }
}

// ---------------- fallback (ws too small / LDS attr fail): direct atomic path ----------------
__global__ __launch_bounds__(256)
void zero_f4(float4* __restrict__ p, int n4) {
    int i = blockIdx.x * blockDim.x + threadIdx.x;
    if (i < n4) p[i] = make_float4(0.f, 0.f, 0.f, 0.f);
}

__global__ __launch_bounds__(256)
void splat_direct(const float* __restrict__ pts, const float* __restrict__ feat,
                  float* __restrict__ out) {
    int i = blockIdx.x * blockDim.x + threadIdx.x;
    if (i >= NPTS) return;
    int b = i >> LOG2P;
    const float* pp = pts + (long long)i * 3;
    float scale = (b < 2) ? 0.5f : 1.0f;
    float* dst = out + ((b < 2) ? 0 : VOLSZ);
    float xf = (pp[0] + 1.f) * 127.5f, yf = (pp[1] + 1.f) * 127.5f, zf = (pp[2] + 1.f) * 127.5f;
    float lxf = floorf(xf), lyf = floorf(yf), lzf = floorf(zf);
    float fx = xf - lxf, fy = yf - lyf, fz = zf - lzf;
    int ix = (int)lxf, iy = (int)lyf, iz = (int)lzf;
    float wv = feat[i] * scale;
    float wx[2] = {1.f - fx, fx}, wy[2] = {1.f - fy, fy}, wz[2] = {1.f - fz, fz};
#pragma unroll
    for (int dz = 0; dz < 2; ++dz) {
        int z2 = iz + dz; if ((unsigned)z2 >= (unsigned)V) continue;
#pragma unroll
        for (int dy = 0; dy < 2; ++dy) {
            int y2 = iy + dy; if ((unsigned)y2 >= (unsigned)V) continue;
            float wzy = wz[dz] * wy[dy] * wv;
            int base = (z2 * V + y2) * V;
#pragma unroll
            for (int dx = 0; dx < 2; ++dx) {
                int x2 = ix + dx; if ((unsigned)x2 >= (unsigned)V) continue;
                unsafeAtomicAdd(dst + base + x2, wzy * wx[dx]);
            }
        }
    }
}

extern "C" void kernel_launch(void* const* d_in, const int* in_sizes, int n_in,
                              void* d_out, int out_size, void* d_ws, size_t ws_size,
                              hipStream_t stream) {
    const float* pts  = (const float*)d_in[0];
    const float* feat = (const float*)d_in[1];
    float* out = (float*)d_out;

    // raise dynamic-LDS cap for the 74KB packed tile (once per process)
    static int lds_ok = -1;
    if (lds_ok < 0) {
        hipError_t err = hipFuncSetAttribute((const void*)splat_cells_k,
                                             hipFuncAttributeMaxDynamicSharedMemorySize,
                                             TWORDS * 8);
        lds_ok = (err == hipSuccess) ? 1 : 0;
    }

    if (ws_size < WS_REQ || !lds_ok) {
        int n4 = out_size / 4;
        zero_f4<<<(n4 + 255) / 256, 256, 0, stream>>>((float4*)out, n4);
        splat_direct<<<(NPTS + 255) / 256, 256, 0, stream>>>(pts, feat, out);
        return;
    }

    char* ws = (char*)d_ws;
    unsigned long long* recs = (unsigned long long*)(ws + R_OFF);
    unsigned* partials       = (unsigned*)(ws + P_OFF);
    unsigned* totals         = (unsigned*)(ws + T_OFF);
    unsigned* bases          = (unsigned*)(ws + B_OFF);
    __half* halo             = (__half*)(ws + H_OFF);

    count_k  <<<NBLK, TPB, 0, stream>>>(pts, partials);
    totals_k <<<NBINS / 256, 256, 0, stream>>>(partials, totals);
    scan_k   <<<1, 1024, 0, stream>>>(totals, bases);
    offsets_k<<<NBINS / 256, 256, 0, stream>>>(partials, bases);
    scatter_k<<<NBLK, TPB, 0, stream>>>(pts, feat, partials, recs);
    splat_cells_k<<<NBINS, STPB, TWORDS * 8, stream>>>(recs, bases, out, halo);
    halo_k   <<<(1u << 23) / 256, 256, 0, stream>>>(halo, out);
}